// Round 13
// baseline (365.229 us; speedup 1.0000x reference)
//
#include <hip/hip_runtime.h>
#include <math.h>

// Problem constants
#define DIMD 512
#define QS 64
#define KS 256
#define WIN 4
#define BATCH 8
#define RANK 32
#define NQ 1024             // q tokens per batch
#define NK 4096             // kv tokens per batch
#define MQ (BATCH*NQ)       // 8192 q rows
#define MK (BATCH*NK)       // 32768 kv rows

typedef unsigned short u16;
typedef __attribute__((ext_vector_type(8))) short bf16x8;  // MFMA A/B frag (8 bf16)
typedef __attribute__((ext_vector_type(4))) float f32x4;   // MFMA C/D frag

__device__ inline u16 f2bf(float x) {
    union { float f; unsigned int u; } v; v.f = x;
    unsigned int r = v.u + 0x7FFF + ((v.u >> 16) & 1);
    return (u16)(r >> 16);
}
__device__ inline float bf2f(u16 x) {
    union { unsigned int u; float f; } v; v.u = ((unsigned int)x) << 16;
    return v.f;
}

// async global->LDS, 16 B per lane. LDS dest = wave-uniform base + lane*16.
__device__ __forceinline__ void gload16(const u16* g, u16* l) {
    __builtin_amdgcn_global_load_lds(
        (const __attribute__((address_space(1))) void*)g,
        (__attribute__((address_space(3))) void*)l, 16, 0, 0);
}

#define WAITV(n) asm volatile("s_waitcnt vmcnt(" #n ")" ::: "memory")

// ===========================================================================
// Device bodies (weight-space, chain-split versions)
// ===========================================================================

// film_h, 16-way i-split: bid in [0,256). 16 d-values per block.
__device__ __forceinline__ void film_h16(
    int bid, const float* __restrict__ ctx0, const float* __restrict__ ctx1,
    const float* __restrict__ Wc0, const float* __restrict__ bc0,
    const float* __restrict__ Wc1, const float* __restrict__ bc1,
    float* __restrict__ h)
{
    int b = bid >> 5;
    int d0 = (bid & 31) * 16;
    int t = threadIdx.x;
    int p = t & 15, dl = t >> 4;
    int d = d0 + dl;
    const float* c0 = ctx0 + b * DIMD;
    const float* c1 = ctx1 + b * DIMD;
    float acc = 0.f;
    #pragma unroll 8
    for (int ii = 0; ii < 32; ii++) {
        int i = p * 32 + ii;
        acc = fmaf(c0[i], Wc0[i * DIMD + d], acc);
        acc = fmaf(c1[i], Wc1[i * DIMD + d], acc);
    }
    acc += __shfl_xor(acc, 1);
    acc += __shfl_xor(acc, 2);
    acc += __shfl_xor(acc, 4);
    acc += __shfl_xor(acc, 8);
    if (p == 0) {
        float v = acc + bc0[d] + bc1[d];
        h[b * DIMD + d] = v / (1.f + expf(-v));
    }
}

// film_gb, 16-way i-split: bid in [0,256)
__device__ __forceinline__ void film_gb16(
    int bid, const float* __restrict__ h, const float* __restrict__ Wf,
    const float* __restrict__ bfv, float* __restrict__ gamma, float* __restrict__ beta)
{
    int b = bid >> 5;
    int d0 = (bid & 31) * 16;
    int t = threadIdx.x;
    int p = t & 15, dl = t >> 4;
    int d = d0 + dl;
    const float* hb = h + b * DIMD;
    float ga = 0.f, be = 0.f;
    #pragma unroll 8
    for (int ii = 0; ii < 32; ii++) {
        int i = p * 32 + ii;
        float hv = hb[i];
        ga = fmaf(hv, Wf[i * 2 * DIMD + d], ga);
        be = fmaf(hv, Wf[i * 2 * DIMD + DIMD + d], be);
    }
    #pragma unroll
    for (int o = 1; o < 16; o <<= 1) {
        ga += __shfl_xor(ga, o);
        be += __shfl_xor(be, o);
    }
    if (p == 0) {
        gamma[b * DIMD + d] = ga + bfv[d];
        beta[b * DIMD + d]  = be + bfv[DIMD + d];
    }
}

// transpose W[512][512] -> bf16 dst[dst_row_off + n][k], i in [0,256)
__device__ __forceinline__ void transpose_body(
    int i, const float* __restrict__ src, u16* __restrict__ dst, int dst_row_off,
    float (*tile)[33])
{
    int t = threadIdx.x;
    int tx = t & 31, ty = t >> 5;
    int bx = (i & 15) * 32;
    int by = (i >> 4) * 32;
    #pragma unroll
    for (int k = 0; k < 4; k++)
        tile[ty + k * 8][tx] = src[(long)(by + ty + k * 8) * DIMD + bx + tx];
    __syncthreads();
    #pragma unroll
    for (int k = 0; k < 4; k++)
        dst[(long)(dst_row_off + bx + ty + k * 8) * DIMD + by + tx] = f2bf(tile[tx][ty + k * 8]);
}

// gatefuse, 4-way j-split: gid in [0,512). 64 (r,k) outputs per block.
__device__ __forceinline__ void gatefuse4(
    int gid, const float* __restrict__ W, const float* __restrict__ Wg,
    u16* __restrict__ dst, int dst_row_off)
{
    int t = threadIdx.x;
    int sp = t & 3;
    int idx = (gid & 255) * 64 + (t >> 2);     // 0..16383
    int r = idx & 31, k = idx >> 5;
    float acc = 0.f;
    #pragma unroll 8
    for (int jj = 0; jj < 128; jj++) {
        int j = sp * 128 + jj;
        acc = fmaf(W[k * DIMD + j], Wg[j * RANK + r], acc);
    }
    acc += __shfl_xor(acc, 1);
    acc += __shfl_xor(acc, 2);
    if (sp == 0) dst[(long)(dst_row_off + r) * DIMD + k] = f2bf(acc);
}

// biascat3: cid 0..3 copy 1024 elems; cid 4 = dot block (32 r x 8-way split)
__device__ __forceinline__ void biascat3_body(
    int cid, const float* __restrict__ b0, const float* __restrict__ b1,
    const float* __restrict__ Wg, float* __restrict__ dst)
{
    int tid = threadIdx.x;
    if (cid < 4) {
        int t = cid * 256 + tid;
        if (t < 512) dst[t] = b0[t];
        else dst[t] = b1[t - 512];
    } else {
        int r = tid >> 3, sp = tid & 7;
        float a = 0.f;
        #pragma unroll 8
        for (int jj = 0; jj < 64; jj++) {
            int j = sp * 64 + jj;
            a = fmaf(b0[j], Wg[j * RANK + r], a);
        }
        a += __shfl_xor(a, 1);
        a += __shfl_xor(a, 2);
        a += __shfl_xor(a, 4);
        if (sp == 0) dst[1024 + r] = a;
    }
}

// biascat2: cid 0..1 copy 512 elems; cid 2 = dot block
__device__ __forceinline__ void biascat2_body(
    int cid, const float* __restrict__ b0, const float* __restrict__ Wg,
    float* __restrict__ dst)
{
    int tid = threadIdx.x;
    if (cid < 2) {
        int t = cid * 256 + tid;
        dst[t] = b0[t];
    } else {
        int r = tid >> 3, sp = tid & 7;
        float a = 0.f;
        #pragma unroll 8
        for (int jj = 0; jj < 64; jj++) {
            int j = sp * 64 + jj;
            a = fmaf(b0[j], Wg[j * RANK + r], a);
        }
        a += __shfl_xor(a, 1);
        a += __shfl_xor(a, 2);
        a += __shfl_xor(a, 4);
        if (sp == 0) dst[512 + r] = a;
    }
}

// ---------------------------------------------------------------------------
// bf16 MFMA GEMM body, BK=32, XOR-swizzled LDS (4-chunk), 2-phase double
// buffer in 32 KB LDS -> 4 blocks/CU (16 waves/CU). smem = 16384 u16.
// buf b: A at b*8192, B at b*8192+4096 (u16 units).
// ---------------------------------------------------------------------------
template<int NSEC, bool BF>
__device__ __forceinline__ void gemm_body(
    int id, const u16* __restrict__ A, const u16* __restrict__ Bt,
    const float* __restrict__ biascat,
    void* __restrict__ C0v, void* __restrict__ C1v, void* __restrict__ Cgv,
    int Nvalid, int nx, int ypg, u16* smem)
{
    int t = threadIdx.x;
    int wave = t >> 6, lane = t & 63;
    int xcd = id & 7, li = id >> 3;
    int by = xcd * ypg + li / nx;
    int bx = li % nx;
    int m0 = by * 128, n0 = bx * 128;
    int mhalf = (wave >> 1) * 64, nhalf = (wave & 1) * 64;
    int lm = lane & 15, quad = lane >> 4;

    // staging (BK=32): per tile, wave w covers rows g*64 + w*16 + (lane>>2),
    // cols (lane&3)*8 pre-swizzled by row&3 = (lane>>2)&3. LDS dest linear.
    int srow = wave * 16 + (lane >> 2);
    int scol = ((lane & 3) ^ ((lane >> 2) & 3)) * 8;
    const u16* Ag = A + (long)(m0 + srow) * DIMD + scol;
    const u16* Bg = Bt + (long)(n0 + srow) * DIMD + scol;
    int loff = wave * 512 + lane * 8;

    f32x4 acc[4][4];
    #pragma unroll
    for (int i = 0; i < 4; i++)
        #pragma unroll
        for (int j = 0; j < 4; j++)
            acc[i][j] = (f32x4){0.f, 0.f, 0.f, 0.f};

    // prologue: stage tile 0 into buf 0
    #pragma unroll
    for (int g = 0; g < 2; g++) {
        gload16(Ag + g * 64 * DIMD, smem + g * 2048 + loff);
        gload16(Bg + g * 64 * DIMD, smem + 4096 + g * 2048 + loff);
    }
    WAITV(0);
    __syncthreads();

    int cur = 0;
    for (int k0 = 0; k0 < DIMD; k0 += 32) {
        if (k0 + 32 < DIMD) {
            u16* Asl = smem + (cur ^ 1) * 8192 + loff;
            u16* Bsl = smem + (cur ^ 1) * 8192 + 4096 + loff;
            #pragma unroll
            for (int g = 0; g < 2; g++) {
                gload16(Ag + k0 + 32 + g * 64 * DIMD, Asl + g * 2048);
                gload16(Bg + k0 + 32 + g * 64 * DIMD, Bsl + g * 2048);
            }
        }
        const u16* As = smem + cur * 8192;
        const u16* Bs = smem + cur * 8192 + 4096;
        bf16x8 af[4], bfr[4];
        #pragma unroll
        for (int i = 0; i < 4; i++) {
            // logical chunk quad of row R lives at physical chunk quad ^ (R&3);
            // R&3 == lm&3 (mhalf, i*16 are 0 mod 4).
            int pc = (quad ^ (lm & 3)) << 3;
            af[i]  = *(const bf16x8*)&As[(mhalf + i * 16 + lm) * 32 + pc];
            bfr[i] = *(const bf16x8*)&Bs[(nhalf + i * 16 + lm) * 32 + pc];
        }
        #pragma unroll
        for (int i = 0; i < 4; i++)
            #pragma unroll
            for (int j = 0; j < 4; j++)
                acc[i][j] = __builtin_amdgcn_mfma_f32_16x16x32_bf16(af[i], bfr[j], acc[i][j], 0, 0, 0);
        WAITV(0);
        __syncthreads();
        cur ^= 1;
    }

    float biasj[4];
    #pragma unroll
    for (int j = 0; j < 4; j++) biasj[j] = biascat[n0 + nhalf + j * 16 + lm];

    if (BF) {
        #pragma unroll
        for (int p = 0; p < 2; p++) {
            __syncthreads();
            #pragma unroll
            for (int ii = 0; ii < 2; ii++) {
                int i = p * 2 + ii;
                #pragma unroll
                for (int j = 0; j < 4; j++)
                    #pragma unroll
                    for (int r = 0; r < 4; r++)
                        smem[(ii * 32 + (wave >> 1) * 16 + quad * 4 + r) * 136 + nhalf + j * 16 + lm] =
                            f2bf(acc[i][j][r] + biasj[j]);
            }
            __syncthreads();
            #pragma unroll
            for (int u = 0; u < 4; u++) {
                int cch = t + u * 256;            // 0..1023
                int R = cch >> 4, ci = cch & 15;  // R 0..63
                int i = p * 2 + (R >> 5);
                int Rr = R & 31;
                long grow = m0 + (Rr >> 4) * 64 + i * 16 + (Rr & 15);
                int gcol = n0 + ci * 8;
                int4 val = *(const int4*)&smem[R * 136 + ci * 8];
                if (NSEC == 1) {
                    *(int4*)((u16*)C0v + grow * 512 + gcol) = val;
                } else if (NSEC == 2) {
                    if (gcol < 512)          *(int4*)((u16*)C0v + grow * 512 + gcol) = val;
                    else if (gcol < Nvalid)  *(int4*)((u16*)Cgv + grow * 32 + (gcol - 512)) = val;
                } else {
                    if (gcol < 512)          *(int4*)((u16*)C0v + grow * 512 + gcol) = val;
                    else if (gcol < 1024)    *(int4*)((u16*)C1v + grow * 512 + (gcol - 512)) = val;
                    else if (gcol < Nvalid)  *(int4*)((u16*)Cgv + grow * 32 + (gcol - 1024)) = val;
                }
            }
        }
    } else {
        float* Stg = (float*)smem;   // 32*132*4B = 16.9 KB <= 32 KB
        for (int i = 0; i < 4; i++) {
            __syncthreads();
            #pragma unroll
            for (int j = 0; j < 4; j++)
                #pragma unroll
                for (int r = 0; r < 4; r++)
                    Stg[((wave >> 1) * 16 + quad * 4 + r) * 132 + nhalf + j * 16 + lm] =
                        acc[i][j][r] + biasj[j];
            __syncthreads();
            #pragma unroll
            for (int u = 0; u < 4; u++) {
                int cch = t + u * 256;
                int R = cch >> 5, ci = cch & 31;
                long grow = m0 + (R >> 4) * 64 + i * 16 + (R & 15);
                int gcol = n0 + ci * 4;
                *(float4*)((float*)C0v + grow * 512 + gcol) = *(const float4*)&Stg[R * 132 + ci * 4];
            }
        }
    }
}

// ===========================================================================
// K1a: prep_w — weight-space work only (small LDS -> high occupancy).
// ===========================================================================
#define PW_FILMH   256
#define PW_GATE    (PW_FILMH + 512)    // 768
#define PW_BIAS    (PW_GATE + 8)       // 776
#define PW_TOTAL   (PW_BIAS + 1024)    // 1800

__global__ __launch_bounds__(256) void prep_w_kernel(
    const float* __restrict__ ctx0, const float* __restrict__ ctx1,
    const float* __restrict__ Wc0, const float* __restrict__ bc0,
    const float* __restrict__ Wc1, const float* __restrict__ bc1,
    float* __restrict__ h,
    const float* __restrict__ Wk, const float* __restrict__ Wv,
    const float* __restrict__ Wq, const float* __restrict__ Wo,
    u16* __restrict__ Btkv, u16* __restrict__ Btq, u16* __restrict__ Bto,
    const float* __restrict__ Wgk, const float* __restrict__ Wgq,
    const float* __restrict__ bk, const float* __restrict__ bv,
    const float* __restrict__ bq, float* __restrict__ biaskv,
    float* __restrict__ biasq)
{
    __shared__ float tile[32][33];
    int bid = blockIdx.x;
    if (bid < PW_FILMH) {
        film_h16(bid, ctx0, ctx1, Wc0, bc0, Wc1, bc1, h);
    } else if (bid < PW_GATE) {
        int gid = bid - PW_FILMH;
        if (gid < 256) gatefuse4(gid, Wk, Wgk, Btkv, 1024);
        else           gatefuse4(gid, Wq, Wgq, Btq, 512);
    } else if (bid < PW_BIAS) {
        int cid = bid - PW_GATE;
        if (cid < 5) biascat3_body(cid, bk, bv, Wgk, biaskv);
        else         biascat2_body(cid - 5, bq, Wgq, biasq);
    } else {
        int tid = bid - PW_BIAS;
        int which = tid >> 8, i = tid & 255;
        if (which == 0)      transpose_body(i, Wk, Btkv, 0, tile);
        else if (which == 1) transpose_body(i, Wv, Btkv, 512, tile);
        else if (which == 2) transpose_body(i, Wq, Btq, 0, tile);
        else                 transpose_body(i, Wo, Bto, 0, tile);
    }
}

// ===========================================================================
// K1b: prep_s — max-TLP streaming: ZERO LDS, 2048 blocks x 4 waves
// = 32 waves/CU. Grid-stride, one row per wave-iteration.
// ===========================================================================
#define PS_BLOCKS 2048

__global__ __launch_bounds__(256) void prep_s_kernel(
    const float* __restrict__ query, float* __restrict__ mu_q, float* __restrict__ rs_q,
    const float* __restrict__ source, const float* __restrict__ kvn_g,
    const float* __restrict__ kvn_b, u16* __restrict__ sln)
{
    int lane = threadIdx.x & 63;
    int gw = blockIdx.x * 4 + (threadIdx.x >> 6);
    int c = lane * 8;
    float4 g0 = *(const float4*)&kvn_g[c], g1 = *(const float4*)&kvn_g[c + 4];
    float4 b0 = *(const float4*)&kvn_b[c], b1 = *(const float4*)&kvn_b[c + 4];

    for (long row = gw; row < (long)(MQ + MK); row += PS_BLOCKS * 4) {
        const float* x = (row < MQ)
            ? query + row * DIMD + c
            : source + (row - MQ) * DIMD + c;
        float4 a = *(const float4*)x;
        float4 b = *(const float4*)(x + 4);
        float s = a.x + a.y + a.z + a.w + b.x + b.y + b.z + b.w;
        float q = a.x*a.x + a.y*a.y + a.z*a.z + a.w*a.w
                + b.x*b.x + b.y*b.y + b.z*b.z + b.w*b.w;
        #pragma unroll
        for (int o = 1; o < 64; o <<= 1) {
            s += __shfl_xor(s, o);
            q += __shfl_xor(q, o);
        }
        float mu = s * (1.f / DIMD);
        float rs = rsqrtf(q * (1.f / DIMD) - mu * mu + 1e-5f);
        if (row < MQ) {
            if (lane == 0) {
                mu_q[row] = mu;
                rs_q[row] = rs;
            }
        } else {
            u16 o8[8];
            o8[0] = f2bf((a.x - mu) * rs * g0.x + b0.x);
            o8[1] = f2bf((a.y - mu) * rs * g0.y + b0.y);
            o8[2] = f2bf((a.z - mu) * rs * g0.z + b0.z);
            o8[3] = f2bf((a.w - mu) * rs * g0.w + b0.w);
            o8[4] = f2bf((b.x - mu) * rs * g1.x + b1.x);
            o8[5] = f2bf((b.y - mu) * rs * g1.y + b1.y);
            o8[6] = f2bf((b.z - mu) * rs * g1.z + b1.z);
            o8[7] = f2bf((b.w - mu) * rs * g1.w + b1.w);
            *(int4*)&sln[(row - MQ) * DIMD + c] = *(const int4*)o8;
        }
    }
}

// ===========================================================================
// K2: film_gb (256 blocks) + kv projection GEMM (2304 blocks), BK=32 dbuf
// ===========================================================================
__global__ __launch_bounds__(256) void kv_kernel(
    const float* __restrict__ h, const float* __restrict__ Wf,
    const float* __restrict__ bfv, float* __restrict__ gamma, float* __restrict__ beta,
    const u16* __restrict__ sln, const u16* __restrict__ Btkv,
    const float* __restrict__ biaskv,
    u16* __restrict__ kp, u16* __restrict__ vp, u16* __restrict__ gk)
{
    __shared__ u16 smem[16384];
    int bid = blockIdx.x;
    if (bid < 256) {
        film_gb16(bid, h, Wf, bfv, gamma, beta);
    } else {
        gemm_body<3, true>(bid - 256, sln, Btkv, biaskv, kp, vp, gk, 1056, 9, 32, smem);
    }
}

// ===========================================================================
// K3: q projection GEMM with LN+FiLM fused into A-staging (BK=32, unchanged)
// ===========================================================================
__global__ __launch_bounds__(256) void qproj_kernel(
    const float* __restrict__ query, const float* __restrict__ mu_q,
    const float* __restrict__ rs_q, const float* __restrict__ qn_g,
    const float* __restrict__ qn_b, const float* __restrict__ gamma,
    const float* __restrict__ beta, const u16* __restrict__ Btq,
    const float* __restrict__ biasq, u16* __restrict__ qp, u16* __restrict__ gq)
{
    __shared__ u16 smem[8192];
    u16* As = smem;
    u16* Bs = smem + 4096;

    int t = threadIdx.x;
    int wave = t >> 6, lane = t & 63;
    int id = blockIdx.x;
    int xcd = id & 7, li = id >> 3;
    int by = xcd * 8 + li / 5;
    int bx = li % 5;
    int m0 = by * 128, n0 = bx * 128;
    int mhalf = (wave >> 1) * 64, nhalf = (wave & 1) * 64;
    int lm = lane & 15, quad = lane >> 4;
    int bt = m0 >> 10;                    // batch (128 | 1024, uniform per block)

    int srow = wave * 32 + (lane >> 2);
    int scol = (lane & 3) * 8;
    const u16* Bg = Btq + (long)(n0 + srow) * DIMD + scol;
    u16* Bsl = Bs + wave * 1024 + lane * 8;

    f32x4 acc[4][4];
    #pragma unroll
    for (int i = 0; i < 4; i++)
        #pragma unroll
        for (int j = 0; j < 4; j++)
            acc[i][j] = (f32x4){0.f, 0.f, 0.f, 0.f};

    for (int k0 = 0; k0 < DIMD; k0 += 32) {
        __syncthreads();
        gload16(Bg + k0, Bsl);
        gload16(Bg + 16 * DIMD + k0, Bsl + 512);
        // A staging: LN+FiLM inline, 2 chunks of 8 elements per thread
        #pragma unroll
        for (int u = 0; u < 2; u++) {
            int idx = t + u * 256;            // 0..511
            int r = idx >> 2;                 // row 0..127
            int c8 = (idx & 3) * 8;           // col 0,8,16,24
            long grow = m0 + r;
            int col = k0 + c8;
            const float* xp = &query[grow * DIMD + col];
            float4 x0 = *(const float4*)xp, x1 = *(const float4*)(xp + 4);
            float mu = mu_q[grow], rs = rs_q[grow];
            float4 g0 = *(const float4*)&qn_g[col], g1 = *(const float4*)&qn_g[col + 4];
            float4 b0 = *(const float4*)&qn_b[col], b1 = *(const float4*)&qn_b[col + 4];
            const float* gp = gamma + bt * DIMD + col;
            const float* bp = beta + bt * DIMD + col;
            float4 gm0 = *(const float4*)gp, gm1 = *(const float4*)(gp + 4);
            float4 be0 = *(const float4*)bp, be1 = *(const float4*)(bp + 4);
            u16 o8[8];
            o8[0] = f2bf(((x0.x - mu) * rs * g0.x + b0.x) * (1.f + gm0.x) + be0.x);
            o8[1] = f2bf(((x0.y - mu) * rs * g0.y + b0.y) * (1.f + gm0.y) + be0.y);
            o8[2] = f2bf(((x0.z - mu) * rs * g0.z + b0.z) * (1.f + gm0.z) + be0.z);
            o8[3] = f2bf(((x0.w - mu) * rs * g0.w + b0.w) * (1.f + gm0.w) + be0.w);
            o8[4] = f2bf(((x1.x - mu) * rs * g1.x + b1.x) * (1.f + gm1.x) + be1.x);
            o8[5] = f2bf(((x1.y - mu) * rs * g1.y + b1.y) * (1.f + gm1.y) + be1.y);
            o8[6] = f2bf(((x1.z - mu) * rs * g1.z + b1.z) * (1.f + gm1.z) + be1.z);
            o8[7] = f2bf(((x1.w - mu) * rs * g1.w + b1.w) * (1.f + gm1.w) + be1.w);
            *(int4*)&As[r * 32 + c8] = *(const int4*)o8;
        }
        __syncthreads();
        bf16x8 af[4], bfr[4];
        #pragma unroll
        for (int i = 0; i < 4; i++) {
            af[i]  = *(const bf16x8*)&As[(mhalf + i * 16 + lm) * 32 + quad * 8];
            bfr[i] = *(const bf16x8*)&Bs[(nhalf + i * 16 + lm) * 32 + quad * 8];
        }
        #pragma unroll
        for (int i = 0; i < 4; i++)
            #pragma unroll
            for (int j = 0; j < 4; j++)
                acc[i][j] = __builtin_amdgcn_mfma_f32_16x16x32_bf16(af[i], bfr[j], acc[i][j], 0, 0, 0);
    }

    float biasj[4];
    #pragma unroll
    for (int j = 0; j < 4; j++) biasj[j] = biasq[n0 + nhalf + j * 16 + lm];

    for (int i = 0; i < 4; i++) {
        __syncthreads();
        #pragma unroll
        for (int j = 0; j < 4; j++)
            #pragma unroll
            for (int r = 0; r < 4; r++)
                smem[((wave >> 1) * 16 + quad * 4 + r) * 128 + nhalf + j * 16 + lm] =
                    f2bf(acc[i][j][r] + biasj[j]);
        __syncthreads();
        #pragma unroll
        for (int u = 0; u < 2; u++) {
            int cch = t + u * 256;
            int R = cch >> 4, ci = cch & 15;
            long grow = m0 + (R >> 4) * 64 + i * 16 + (R & 15);
            int gcol = n0 + ci * 8;
            int4 val = *(const int4*)&smem[R * 128 + ci * 8];
            if (gcol < 512)       *(int4*)(qp + grow * 512 + gcol) = val;
            else if (gcol < 544)  *(int4*)(gq + grow * 32 + (gcol - 512)) = val;
        }
    }
}

// ===========================================================================
// K5: output projection (fp32 out), BK=32 dbuf GEMM
// ===========================================================================
__global__ __launch_bounds__(256) void ogemm_kernel(
    const u16* __restrict__ ctxb, const u16* __restrict__ Bto,
    const float* __restrict__ bo, float* __restrict__ out)
{
    __shared__ u16 smem[16384];
    gemm_body<1, false>(blockIdx.x, ctxb, Bto, bo, out, nullptr, nullptr, 512, 4, 8, smem);
}

// ===========================================================================
// K4: Flash-style local attention, 2-step-deep register K/V prefetch.
// ===========================================================================
__global__ __launch_bounds__(256, 2) void attn_kernel(
    const u16* __restrict__ q_bf, const u16* __restrict__ k_bf,
    const u16* __restrict__ v_bf, const u16* __restrict__ gq_bf,
    const u16* __restrict__ gk_bf, u16* __restrict__ ctx)
{
    __shared__ u16 Ks[16 * 512];
    __shared__ u16 Vt[512 * 32];
    __shared__ u16 Pb[16 * 40];
    __shared__ float part[4][16][16];
    __shared__ float Gb[16][16];
    __shared__ float alphap[16];
    __shared__ float linv[16];

    int blk = blockIdx.x;
    int b = blk >> 6, qs = blk & 63;
    int center = (int)(qs * (255.0f / 63.0f) + 0.5f);
    int lo = center - WIN; if (lo < 0) lo = 0;
    int hi = center + WIN; if (hi > KS - 1) hi = KS - 1;
    int nst = hi - lo + 1;
    long rowq0 = (long)b * NQ + qs * 16;
    long rowk0 = (long)b * NK + lo * 16;

    int t = threadIdx.x;
    int wave = t >> 6, lane = t & 63;
    int lm = lane & 15, quad = lane >> 4;
    int qi = t >> 4, ki = t & 15;

    bf16x8 qf[4];
    #pragma unroll
    for (int f = 0; f < 4; f++)
        qf[f] = *(const bf16x8*)&q_bf[(rowq0 + lm) * DIMD + wave * 128 + f * 32 + quad * 8];
    bf16x8 gqf;
    if (wave == 3) gqf = *(const bf16x8*)&gq_bf[(rowq0 + lm) * RANK + quad * 8];

    // 2-deep prefetch register sets
    int4 kA[4], vA[4], kB[4], vB[4];

    auto loadset = [&](int s, int4 (&kp_)[4], int4 (&vp_)[4]) {
        long rk = rowk0 + (long)s * 16;
        #pragma unroll
        for (int u = 0; u < 4; u++) {
            int idx = u * 256 + t;
            kp_[u] = *(const int4*)&k_bf[(rk + (idx >> 6)) * DIMD + (idx & 63) * 8];
            int vkv = (idx >> 2) & 15, vdc = (idx & 3) | ((idx >> 6) << 2);
            vp_[u] = *(const int4*)&v_bf[(rk + vkv) * DIMD + vdc * 8];
        }
    };

    loadset(0, kA, vA);
    if (nst > 1) loadset(1, kB, vB);

    float m_run = -1e30f, l_run = 0.f;
    f32x4 acc[8];
    #pragma unroll
    for (int j = 0; j < 8; j++) acc[j] = (f32x4){0.f, 0.f, 0.f, 0.f};

    const float scale = 0.044194173824159216f;   // 512^-0.5
    const float grs = 0.17677669529663687f;      // 32^-0.5

    auto step_body = [&](int s, int4 (&kcur)[4], int4 (&vcur)[4]) {
        int half = s & 1;
        #pragma unroll
        for (int u = 0; u < 4; u++) {
            int idx = u * 256 + t;
            int row = idx >> 6, c = idx & 63;
            *(int4*)&Ks[row * 512 + (c ^ (row & 7)) * 8] = kcur[u];
            int vkv = (idx >> 2) & 15, vdc = (idx & 3) | ((idx >> 6) << 2);
            int kvp = half * 16 + vkv;
            u16 vv[8];
            *(int4*)vv = vcur[u];
            #pragma unroll
            for (int i = 0; i < 8; i++) {
                int d = vdc * 8 + i;
                Vt[d * 32 + (((kvp >> 3) ^ (d & 3)) << 3) + (kvp & 7)] = vv[i];
            }
        }
        __syncthreads();
        if (s + 2 < nst) loadset(s + 2, kcur, vcur);

        f32x4 sacc = (f32x4){0.f, 0.f, 0.f, 0.f};
        #pragma unroll
        for (int f = 0; f < 4; f++) {
            int cidx = wave * 16 + f * 4 + quad;
            bf16x8 kf = *(const bf16x8*)&Ks[lm * 512 + (cidx ^ (lm & 7)) * 8];
            sacc = __builtin_amdgcn_mfma_f32_16x16x32_bf16(qf[f], kf, sacc, 0, 0, 0);
        }
        #pragma unroll
        for (int r = 0; r < 4; r++) part[wave][quad * 4 + r][lm] = sacc[r];
        if (wave == 3) {
            bf16x8 gkf = *(const bf16x8*)&gk_bf[(rowk0 + (long)s * 16 + lm) * RANK + quad * 8];
            f32x4 gacc = (f32x4){0.f, 0.f, 0.f, 0.f};
            gacc = __builtin_amdgcn_mfma_f32_16x16x32_bf16(gqf, gkf, gacc, 0, 0, 0);
            #pragma unroll
            for (int r = 0; r < 4; r++) Gb[quad * 4 + r][lm] = gacc[r];
        }
        __syncthreads();
        float sv = (part[0][qi][ki] + part[1][qi][ki] + part[2][qi][ki] + part[3][qi][ki]) * scale;
        float gl = Gb[qi][ki] * grs;
        float sig = 1.f / (1.f + expf(-gl));
        sv += logf(sig + 1e-6f);
        float mx = sv;
        mx = fmaxf(mx, __shfl_xor(mx, 1));
        mx = fmaxf(mx, __shfl_xor(mx, 2));
        mx = fmaxf(mx, __shfl_xor(mx, 4));
        mx = fmaxf(mx, __shfl_xor(mx, 8));
        float m_new = fmaxf(m_run, mx);
        float p = expf(sv - m_new);
        float ps = p;
        ps += __shfl_xor(ps, 1);
        ps += __shfl_xor(ps, 2);
        ps += __shfl_xor(ps, 4);
        ps += __shfl_xor(ps, 8);
        float alpha = expf(m_run - m_new);
        l_run = l_run * alpha + ps;
        m_run = m_new;
        Pb[qi * 40 + half * 16 + ki] = f2bf(p);
        if (half == 1) {
            Pb[qi * 40 + ki] = f2bf(bf2f(Pb[qi * 40 + ki]) * alpha);
        }
        bool dopv = (half == 1) || (s == nst - 1);
        if (dopv && half == 0) Pb[qi * 40 + 16 + ki] = 0;
        if (ki == 0) {
            if (half == 0) alphap[qi] = alpha;
            else           alphap[qi] *= alpha;
            if (s == nst - 1) linv[qi] = 1.f / l_run;
        }
        __syncthreads();
        if (dopv) {
            float ar[4];
            #pragma unroll
            for (int r = 0; r < 4; r++) ar[r] = alphap[quad * 4 + r];
            #pragma unroll
            for (int j = 0; j < 8; j++)
                #pragma unroll
                for (int r = 0; r < 4; r++) acc[j][r] *= ar[r];
            bf16x8 pf = *(const bf16x8*)&Pb[lm * 40 + quad * 8];
            #pragma unroll
            for (int j = 0; j < 8; j++) {
                int d = wave * 128 + j * 16 + lm;
                bf16x8 vf = *(const bf16x8*)&Vt[d * 32 + ((quad ^ (d & 3)) << 3)];
                acc[j] = __builtin_amdgcn_mfma_f32_16x16x32_bf16(pf, vf, acc[j], 0, 0, 0);
            }
            __syncthreads();
        }
    };

    for (int s = 0; s < nst; s++) {
        if ((s & 1) == 0) step_body(s, kA, vA);
        else              step_body(s, kB, vB);
    }

    float li[4];
    #pragma unroll
    for (int r = 0; r < 4; r++) li[r] = linv[quad * 4 + r];
    #pragma unroll
    for (int j = 0; j < 8; j++) {
        int d = wave * 128 + j * 16 + lm;
        #pragma unroll
        for (int r = 0; r < 4; r++)
            ctx[(rowq0 + quad * 4 + r) * DIMD + d] = f2bf(acc[j][r] * li[r]);
    }
}

// ---------------------------------------------------------------------------
extern "C" void kernel_launch(void* const* d_in, const int* in_sizes, int n_in,
                              void* d_out, int out_size, void* d_ws, size_t ws_size,
                              hipStream_t stream) {
    const float* query  = (const float*)d_in[0];
    const float* source = (const float*)d_in[1];
    const float* ctx0   = (const float*)d_in[2];
    const float* ctx1   = (const float*)d_in[3];
    // d_in[4] = mask: structurally known local window, unused
    const float* qn_g  = (const float*)d_in[5];
    const float* qn_b  = (const float*)d_in[6];
    const float* kvn_g = (const float*)d_in[7];
    const float* kvn_b = (const float*)d_in[8];
    const float* Wq = (const float*)d_in[9];   const float* bq = (const float*)d_in[10];
    const float* Wk = (const float*)d_in[11];  const float* bk = (const float*)d_in[12];
    const float* Wv = (const float*)d_in[13];  const float* bv = (const float*)d_in[14];
    const float* Wo = (const float*)d_in[15];  const float* bo = (const float*)d_in[16];
    const float* Wgq = (const float*)d_in[17];
    const float* Wgk = (const float*)d_in[18];
    const float* Wc0 = (const float*)d_in[19]; const float* bc0 = (const float*)d_in[20];
    const float* Wc1 = (const float*)d_in[21]; const float* bc1 = (const float*)d_in[22];
    const float* Wf  = (const float*)d_in[23]; const float* bfv = (const float*)d_in[24];

    // ---- workspace layout ----
    float* ws = (float*)d_ws;
    float* h      = ws;                         // 4096
    float* gamma  = h + 4096;                   // 4096
    float* beta   = gamma + 4096;               // 4096
    float* biaskv = beta + 4096;                // 1152
    float* biasq  = biaskv + 1152;              // 640
    float* mu_q   = biasq + 640;                // 8192
    float* rs_q   = mu_q + 8192;                // 8192
    u16* u = (u16*)(rs_q + 8192);
    u16* sln  = u;                 u += (long)MK * DIMD;   // LN(source) bf16
    u16* kp   = u;                 u += (long)MK * DIMD;   // k proj bf16
    u16* vp   = u;                 u += (long)MK * DIMD;   // v proj bf16
    u16* gk   = u;                 u += (long)MK * RANK;   // gate_k bf16
    u16* gq   = u;                 u += (long)MQ * RANK;   // gate_q bf16
    u16* qp   = u;                 u += (long)MQ * DIMD;   // q proj bf16
    u16* ctxb = u;                 u += (long)MQ * DIMD;   // attention output bf16
    u16* Btkv = u;                 u += 1152L * DIMD;      // [Wk^T | Wv^T | (Wk·Wgk)^T]
    u16* Btq  = u;                 u += 640L * DIMD;       // [Wq^T | (Wq·Wgq)^T]
    u16* Bto  = u;                 u += 512L * DIMD;       // Wo^T
    float* out = (float*)d_out;

    // K1a: weight-space prep (small LDS, chain-split bodies)
    prep_w_kernel<<<PW_TOTAL, 256, 0, stream>>>(
        ctx0, ctx1, Wc0, bc0, Wc1, bc1, h,
        Wk, Wv, Wq, Wo, Btkv, Btq, Bto,
        Wgk, Wgq, bk, bv, bq, biaskv, biasq);

    // K1b: max-TLP streaming (stats + norm0), zero LDS, 32 waves/CU
    prep_s_kernel<<<PS_BLOCKS, 256, 0, stream>>>(
        query, mu_q, rs_q, source, kvn_g, kvn_b, sln);

    // K2: film_gb + kv projection GEMM (BK=32 dbuf, 32 KB LDS -> 4 blocks/CU)
    kv_kernel<<<256 + 2304, 256, 0, stream>>>(
        h, Wf, bfv, gamma, beta, sln, Btkv, biaskv, kp, vp, gk);

    // K3: q projection GEMM (LN+FiLM inline)
    qproj_kernel<<<320, 256, 0, stream>>>(
        query, mu_q, rs_q, qn_g, qn_b, gamma, beta, Btq, biasq, qp, gq);

    // K4: flash local attention (2-deep K/V prefetch)
    attn_kernel<<<BATCH * QS, 256, 0, stream>>>(qp, kp, vp, gq, gk, ctxb);

    // K5: output projection (fp32 out)
    ogemm_kernel<<<256, 256, 0, stream>>>(ctxb, Bto, bo, out);
}

// Round 14
// 343.179 us; speedup vs baseline: 1.0643x; 1.0643x over previous
//
#include <hip/hip_runtime.h>
#include <math.h>

// Problem constants
#define DIMD 512
#define QS 64
#define KS 256
#define WIN 4
#define BATCH 8
#define RANK 32
#define NQ 1024             // q tokens per batch
#define NK 4096             // kv tokens per batch
#define MQ (BATCH*NQ)       // 8192 q rows
#define MK (BATCH*NK)       // 32768 kv rows

typedef unsigned short u16;
typedef __attribute__((ext_vector_type(8))) short bf16x8;  // MFMA A/B frag (8 bf16)
typedef __attribute__((ext_vector_type(4))) float f32x4;   // MFMA C/D frag

__device__ inline u16 f2bf(float x) {
    union { float f; unsigned int u; } v; v.f = x;
    unsigned int r = v.u + 0x7FFF + ((v.u >> 16) & 1);
    return (u16)(r >> 16);
}
__device__ inline float bf2f(u16 x) {
    union { unsigned int u; float f; } v; v.u = ((unsigned int)x) << 16;
    return v.f;
}

// async global->LDS, 16 B per lane. LDS dest = wave-uniform base + lane*16.
__device__ __forceinline__ void gload16(const u16* g, u16* l) {
    __builtin_amdgcn_global_load_lds(
        (const __attribute__((address_space(1))) void*)g,
        (__attribute__((address_space(3))) void*)l, 16, 0, 0);
}

#define WAITV(n) asm volatile("s_waitcnt vmcnt(" #n ")" ::: "memory")

// ===========================================================================
// Device bodies (weight-space, chain-split versions)
// ===========================================================================

// film_h, 16-way i-split: bid in [0,256). 16 d-values per block.
__device__ __forceinline__ void film_h16(
    int bid, const float* __restrict__ ctx0, const float* __restrict__ ctx1,
    const float* __restrict__ Wc0, const float* __restrict__ bc0,
    const float* __restrict__ Wc1, const float* __restrict__ bc1,
    float* __restrict__ h)
{
    int b = bid >> 5;
    int d0 = (bid & 31) * 16;
    int t = threadIdx.x;
    int p = t & 15, dl = t >> 4;
    int d = d0 + dl;
    const float* c0 = ctx0 + b * DIMD;
    const float* c1 = ctx1 + b * DIMD;
    float acc = 0.f;
    #pragma unroll 8
    for (int ii = 0; ii < 32; ii++) {
        int i = p * 32 + ii;
        acc = fmaf(c0[i], Wc0[i * DIMD + d], acc);
        acc = fmaf(c1[i], Wc1[i * DIMD + d], acc);
    }
    acc += __shfl_xor(acc, 1);
    acc += __shfl_xor(acc, 2);
    acc += __shfl_xor(acc, 4);
    acc += __shfl_xor(acc, 8);
    if (p == 0) {
        float v = acc + bc0[d] + bc1[d];
        h[b * DIMD + d] = v / (1.f + expf(-v));
    }
}

// film_gb, 16-way i-split: bid in [0,256)
__device__ __forceinline__ void film_gb16(
    int bid, const float* __restrict__ h, const float* __restrict__ Wf,
    const float* __restrict__ bfv, float* __restrict__ gamma, float* __restrict__ beta)
{
    int b = bid >> 5;
    int d0 = (bid & 31) * 16;
    int t = threadIdx.x;
    int p = t & 15, dl = t >> 4;
    int d = d0 + dl;
    const float* hb = h + b * DIMD;
    float ga = 0.f, be = 0.f;
    #pragma unroll 8
    for (int ii = 0; ii < 32; ii++) {
        int i = p * 32 + ii;
        float hv = hb[i];
        ga = fmaf(hv, Wf[i * 2 * DIMD + d], ga);
        be = fmaf(hv, Wf[i * 2 * DIMD + DIMD + d], be);
    }
    #pragma unroll
    for (int o = 1; o < 16; o <<= 1) {
        ga += __shfl_xor(ga, o);
        be += __shfl_xor(be, o);
    }
    if (p == 0) {
        gamma[b * DIMD + d] = ga + bfv[d];
        beta[b * DIMD + d]  = be + bfv[DIMD + d];
    }
}

// transpose W[512][512] -> bf16 dst[dst_row_off + n][k], i in [0,256)
__device__ __forceinline__ void transpose_body(
    int i, const float* __restrict__ src, u16* __restrict__ dst, int dst_row_off,
    float (*tile)[33])
{
    int t = threadIdx.x;
    int tx = t & 31, ty = t >> 5;
    int bx = (i & 15) * 32;
    int by = (i >> 4) * 32;
    #pragma unroll
    for (int k = 0; k < 4; k++)
        tile[ty + k * 8][tx] = src[(long)(by + ty + k * 8) * DIMD + bx + tx];
    __syncthreads();
    #pragma unroll
    for (int k = 0; k < 4; k++)
        dst[(long)(dst_row_off + bx + ty + k * 8) * DIMD + by + tx] = f2bf(tile[tx][ty + k * 8]);
}

// gatefuse, 4-way j-split: gid in [0,512). 64 (r,k) outputs per block.
__device__ __forceinline__ void gatefuse4(
    int gid, const float* __restrict__ W, const float* __restrict__ Wg,
    u16* __restrict__ dst, int dst_row_off)
{
    int t = threadIdx.x;
    int sp = t & 3;
    int idx = (gid & 255) * 64 + (t >> 2);     // 0..16383
    int r = idx & 31, k = idx >> 5;
    float acc = 0.f;
    #pragma unroll 8
    for (int jj = 0; jj < 128; jj++) {
        int j = sp * 128 + jj;
        acc = fmaf(W[k * DIMD + j], Wg[j * RANK + r], acc);
    }
    acc += __shfl_xor(acc, 1);
    acc += __shfl_xor(acc, 2);
    if (sp == 0) dst[(long)(dst_row_off + r) * DIMD + k] = f2bf(acc);
}

// biascat3: cid 0..3 copy 1024 elems; cid 4 = dot block (32 r x 8-way split)
__device__ __forceinline__ void biascat3_body(
    int cid, const float* __restrict__ b0, const float* __restrict__ b1,
    const float* __restrict__ Wg, float* __restrict__ dst)
{
    int tid = threadIdx.x;
    if (cid < 4) {
        int t = cid * 256 + tid;
        if (t < 512) dst[t] = b0[t];
        else dst[t] = b1[t - 512];
    } else {
        int r = tid >> 3, sp = tid & 7;
        float a = 0.f;
        #pragma unroll 8
        for (int jj = 0; jj < 64; jj++) {
            int j = sp * 64 + jj;
            a = fmaf(b0[j], Wg[j * RANK + r], a);
        }
        a += __shfl_xor(a, 1);
        a += __shfl_xor(a, 2);
        a += __shfl_xor(a, 4);
        if (sp == 0) dst[1024 + r] = a;
    }
}

// biascat2: cid 0..1 copy 512 elems; cid 2 = dot block
__device__ __forceinline__ void biascat2_body(
    int cid, const float* __restrict__ b0, const float* __restrict__ Wg,
    float* __restrict__ dst)
{
    int tid = threadIdx.x;
    if (cid < 2) {
        int t = cid * 256 + tid;
        dst[t] = b0[t];
    } else {
        int r = tid >> 3, sp = tid & 7;
        float a = 0.f;
        #pragma unroll 8
        for (int jj = 0; jj < 64; jj++) {
            int j = sp * 64 + jj;
            a = fmaf(b0[j], Wg[j * RANK + r], a);
        }
        a += __shfl_xor(a, 1);
        a += __shfl_xor(a, 2);
        a += __shfl_xor(a, 4);
        if (sp == 0) dst[512 + r] = a;
    }
}

// ---------------------------------------------------------------------------
// bf16 MFMA GEMM body, BK=64, XOR-swizzled LDS, counted-vmcnt 2-deep
// double-buffer (T4): raw s_barrier + WAITV(8) keeps the next tile's 8
// loads in flight across the barrier (no vmcnt(0) drain in steady state).
// smem must be 32768 u16 (64 KB): buf b at smem + b*16384 (A), +8192 (B).
// ---------------------------------------------------------------------------
template<int NSEC, bool BF>
__device__ __forceinline__ void gemm_body(
    int id, const u16* __restrict__ A, const u16* __restrict__ Bt,
    const float* __restrict__ biascat,
    void* __restrict__ C0v, void* __restrict__ C1v, void* __restrict__ Cgv,
    int Nvalid, int nx, int ypg, u16* smem)
{
    int t = threadIdx.x;
    int wave = t >> 6, lane = t & 63;
    int xcd = id & 7, li = id >> 3;
    int by = xcd * ypg + li / nx;
    int bx = li % nx;
    int m0 = by * 128, n0 = bx * 128;
    int mhalf = (wave >> 1) * 64, nhalf = (wave & 1) * 64;
    int lm = lane & 15, quad = lane >> 4;

    int srow = wave * 8 + (lane >> 3);
    int scol = ((lane & 7) ^ (lane >> 3)) * 8;
    const u16* Ag = A + (long)(m0 + srow) * DIMD + scol;
    const u16* Bg = Bt + (long)(n0 + srow) * DIMD + scol;
    int loff = wave * 512 + lane * 8;

    f32x4 acc[4][4];
    #pragma unroll
    for (int i = 0; i < 4; i++)
        #pragma unroll
        for (int j = 0; j < 4; j++)
            acc[i][j] = (f32x4){0.f, 0.f, 0.f, 0.f};

    // prologue: stage tiles 0 and 1 (16 loads/wave outstanding)
    #pragma unroll
    for (int b2 = 0; b2 < 2; b2++) {
        u16* Asl = smem + b2 * 16384 + loff;
        u16* Bsl = smem + b2 * 16384 + 8192 + loff;
        #pragma unroll
        for (int g = 0; g < 4; g++) {
            gload16(Ag + b2 * 64 + g * 32 * DIMD, Asl + g * 2048);
            gload16(Bg + b2 * 64 + g * 32 * DIMD, Bsl + g * 2048);
        }
    }

    #pragma unroll
    for (int kt = 0; kt < 8; kt++) {
        // tile kt's 8 loads are the oldest outstanding; tile kt+1's 8 keep flying
        if (kt == 7) { WAITV(0); } else { WAITV(8); }
        __builtin_amdgcn_sched_barrier(0);
        __builtin_amdgcn_s_barrier();
        __builtin_amdgcn_sched_barrier(0);

        const u16* As = smem + (kt & 1) * 16384;
        const u16* Bs = smem + (kt & 1) * 16384 + 8192;
        #pragma unroll
        for (int kk = 0; kk < 2; kk++) {
            bf16x8 af[4], bfr[4];
            #pragma unroll
            for (int i = 0; i < 4; i++) {
                int pc = ((kk * 4 + quad) ^ (lm & 7)) << 3;
                af[i]  = *(const bf16x8*)&As[(mhalf + i * 16 + lm) * 64 + pc];
                bfr[i] = *(const bf16x8*)&Bs[(nhalf + i * 16 + lm) * 64 + pc];
            }
            #pragma unroll
            for (int i = 0; i < 4; i++)
                #pragma unroll
                for (int j = 0; j < 4; j++)
                    acc[i][j] = __builtin_amdgcn_mfma_f32_16x16x32_bf16(af[i], bfr[j], acc[i][j], 0, 0, 0);
        }
        __builtin_amdgcn_s_barrier();      // all waves done reading buf kt&1
        __builtin_amdgcn_sched_barrier(0);
        if (kt < 6) {
            // stage tile kt+2 into buf (kt&1)
            u16* Asl = smem + (kt & 1) * 16384 + loff;
            u16* Bsl = smem + (kt & 1) * 16384 + 8192 + loff;
            int ko = (kt + 2) * 64;
            #pragma unroll
            for (int g = 0; g < 4; g++) {
                gload16(Ag + ko + g * 32 * DIMD, Asl + g * 2048);
                gload16(Bg + ko + g * 32 * DIMD, Bsl + g * 2048);
            }
        }
    }

    float biasj[4];
    #pragma unroll
    for (int j = 0; j < 4; j++) biasj[j] = biascat[n0 + nhalf + j * 16 + lm];

    if (BF) {
        #pragma unroll
        for (int p = 0; p < 2; p++) {
            __syncthreads();
            #pragma unroll
            for (int ii = 0; ii < 2; ii++) {
                int i = p * 2 + ii;
                #pragma unroll
                for (int j = 0; j < 4; j++)
                    #pragma unroll
                    for (int r = 0; r < 4; r++)
                        smem[(ii * 32 + (wave >> 1) * 16 + quad * 4 + r) * 136 + nhalf + j * 16 + lm] =
                            f2bf(acc[i][j][r] + biasj[j]);
            }
            __syncthreads();
            #pragma unroll
            for (int u = 0; u < 4; u++) {
                int cch = t + u * 256;            // 0..1023
                int R = cch >> 4, ci = cch & 15;  // R 0..63
                int i = p * 2 + (R >> 5);
                int Rr = R & 31;
                long grow = m0 + (Rr >> 4) * 64 + i * 16 + (Rr & 15);
                int gcol = n0 + ci * 8;
                int4 val = *(const int4*)&smem[R * 136 + ci * 8];
                if (NSEC == 1) {
                    *(int4*)((u16*)C0v + grow * 512 + gcol) = val;
                } else if (NSEC == 2) {
                    if (gcol < 512)          *(int4*)((u16*)C0v + grow * 512 + gcol) = val;
                    else if (gcol < Nvalid)  *(int4*)((u16*)Cgv + grow * 32 + (gcol - 512)) = val;
                } else {
                    if (gcol < 512)          *(int4*)((u16*)C0v + grow * 512 + gcol) = val;
                    else if (gcol < 1024)    *(int4*)((u16*)C1v + grow * 512 + (gcol - 512)) = val;
                    else if (gcol < Nvalid)  *(int4*)((u16*)Cgv + grow * 32 + (gcol - 1024)) = val;
                }
            }
        }
    } else {
        float* Stg = (float*)smem;
        for (int i = 0; i < 4; i++) {
            __syncthreads();
            #pragma unroll
            for (int j = 0; j < 4; j++)
                #pragma unroll
                for (int r = 0; r < 4; r++)
                    Stg[((wave >> 1) * 16 + quad * 4 + r) * 132 + nhalf + j * 16 + lm] =
                        acc[i][j][r] + biasj[j];
            __syncthreads();
            #pragma unroll
            for (int u = 0; u < 4; u++) {
                int cch = t + u * 256;
                int R = cch >> 5, ci = cch & 31;
                long grow = m0 + (R >> 4) * 64 + i * 16 + (R & 15);
                int gcol = n0 + ci * 4;
                *(float4*)((float*)C0v + grow * 512 + gcol) = *(const float4*)&Stg[R * 132 + ci * 4];
            }
        }
    }
}

// ===========================================================================
// K1a: prep_w — weight-space work only (small LDS -> high occupancy).
// ===========================================================================
#define PW_FILMH   256
#define PW_GATE    (PW_FILMH + 512)    // 768
#define PW_BIAS    (PW_GATE + 8)       // 776
#define PW_TOTAL   (PW_BIAS + 1024)    // 1800

__global__ __launch_bounds__(256) void prep_w_kernel(
    const float* __restrict__ ctx0, const float* __restrict__ ctx1,
    const float* __restrict__ Wc0, const float* __restrict__ bc0,
    const float* __restrict__ Wc1, const float* __restrict__ bc1,
    float* __restrict__ h,
    const float* __restrict__ Wk, const float* __restrict__ Wv,
    const float* __restrict__ Wq, const float* __restrict__ Wo,
    u16* __restrict__ Btkv, u16* __restrict__ Btq, u16* __restrict__ Bto,
    const float* __restrict__ Wgk, const float* __restrict__ Wgq,
    const float* __restrict__ bk, const float* __restrict__ bv,
    const float* __restrict__ bq, float* __restrict__ biaskv,
    float* __restrict__ biasq)
{
    __shared__ float tile[32][33];
    int bid = blockIdx.x;
    if (bid < PW_FILMH) {
        film_h16(bid, ctx0, ctx1, Wc0, bc0, Wc1, bc1, h);
    } else if (bid < PW_GATE) {
        int gid = bid - PW_FILMH;
        if (gid < 256) gatefuse4(gid, Wk, Wgk, Btkv, 1024);
        else           gatefuse4(gid, Wq, Wgq, Btq, 512);
    } else if (bid < PW_BIAS) {
        int cid = bid - PW_GATE;
        if (cid < 5) biascat3_body(cid, bk, bv, Wgk, biaskv);
        else         biascat2_body(cid - 5, bq, Wgq, biasq);
    } else {
        int tid = bid - PW_BIAS;
        int which = tid >> 8, i = tid & 255;
        if (which == 0)      transpose_body(i, Wk, Btkv, 0, tile);
        else if (which == 1) transpose_body(i, Wv, Btkv, 512, tile);
        else if (which == 2) transpose_body(i, Wq, Btq, 0, tile);
        else                 transpose_body(i, Wo, Bto, 0, tile);
    }
}

// ===========================================================================
// K1b: prep_s — max-TLP streaming: ZERO LDS, 2048 blocks x 4 waves
// = 32 waves/CU. Grid-stride, one row per wave-iteration.
// ===========================================================================
#define PS_BLOCKS 2048

__global__ __launch_bounds__(256) void prep_s_kernel(
    const float* __restrict__ query, float* __restrict__ mu_q, float* __restrict__ rs_q,
    const float* __restrict__ source, const float* __restrict__ kvn_g,
    const float* __restrict__ kvn_b, u16* __restrict__ sln)
{
    int lane = threadIdx.x & 63;
    int gw = blockIdx.x * 4 + (threadIdx.x >> 6);
    int c = lane * 8;
    float4 g0 = *(const float4*)&kvn_g[c], g1 = *(const float4*)&kvn_g[c + 4];
    float4 b0 = *(const float4*)&kvn_b[c], b1 = *(const float4*)&kvn_b[c + 4];

    for (long row = gw; row < (long)(MQ + MK); row += PS_BLOCKS * 4) {
        const float* x = (row < MQ)
            ? query + row * DIMD + c
            : source + (row - MQ) * DIMD + c;
        float4 a = *(const float4*)x;
        float4 b = *(const float4*)(x + 4);
        float s = a.x + a.y + a.z + a.w + b.x + b.y + b.z + b.w;
        float q = a.x*a.x + a.y*a.y + a.z*a.z + a.w*a.w
                + b.x*b.x + b.y*b.y + b.z*b.z + b.w*b.w;
        #pragma unroll
        for (int o = 1; o < 64; o <<= 1) {
            s += __shfl_xor(s, o);
            q += __shfl_xor(q, o);
        }
        float mu = s * (1.f / DIMD);
        float rs = rsqrtf(q * (1.f / DIMD) - mu * mu + 1e-5f);
        if (row < MQ) {
            if (lane == 0) {
                mu_q[row] = mu;
                rs_q[row] = rs;
            }
        } else {
            u16 o8[8];
            o8[0] = f2bf((a.x - mu) * rs * g0.x + b0.x);
            o8[1] = f2bf((a.y - mu) * rs * g0.y + b0.y);
            o8[2] = f2bf((a.z - mu) * rs * g0.z + b0.z);
            o8[3] = f2bf((a.w - mu) * rs * g0.w + b0.w);
            o8[4] = f2bf((b.x - mu) * rs * g1.x + b1.x);
            o8[5] = f2bf((b.y - mu) * rs * g1.y + b1.y);
            o8[6] = f2bf((b.z - mu) * rs * g1.z + b1.z);
            o8[7] = f2bf((b.w - mu) * rs * g1.w + b1.w);
            *(int4*)&sln[(row - MQ) * DIMD + c] = *(const int4*)o8;
        }
    }
}

// ===========================================================================
// K2: film_gb (256 blocks) + kv projection GEMM (2304 blocks), counted dbuf
// ===========================================================================
__global__ __launch_bounds__(256) void kv_kernel(
    const float* __restrict__ h, const float* __restrict__ Wf,
    const float* __restrict__ bfv, float* __restrict__ gamma, float* __restrict__ beta,
    const u16* __restrict__ sln, const u16* __restrict__ Btkv,
    const float* __restrict__ biaskv,
    u16* __restrict__ kp, u16* __restrict__ vp, u16* __restrict__ gk)
{
    __shared__ u16 smem[32768];
    int bid = blockIdx.x;
    if (bid < 256) {
        film_gb16(bid, h, Wf, bfv, gamma, beta);
    } else {
        gemm_body<3, true>(bid - 256, sln, Btkv, biaskv, kp, vp, gk, 1056, 9, 32, smem);
    }
}

// ===========================================================================
// K3: q projection GEMM with LN+FiLM fused into A-staging (BK=32, unchanged)
// ===========================================================================
__global__ __launch_bounds__(256) void qproj_kernel(
    const float* __restrict__ query, const float* __restrict__ mu_q,
    const float* __restrict__ rs_q, const float* __restrict__ qn_g,
    const float* __restrict__ qn_b, const float* __restrict__ gamma,
    const float* __restrict__ beta, const u16* __restrict__ Btq,
    const float* __restrict__ biasq, u16* __restrict__ qp, u16* __restrict__ gq)
{
    __shared__ u16 smem[8192];
    u16* As = smem;
    u16* Bs = smem + 4096;

    int t = threadIdx.x;
    int wave = t >> 6, lane = t & 63;
    int id = blockIdx.x;
    int xcd = id & 7, li = id >> 3;
    int by = xcd * 8 + li / 5;
    int bx = li % 5;
    int m0 = by * 128, n0 = bx * 128;
    int mhalf = (wave >> 1) * 64, nhalf = (wave & 1) * 64;
    int lm = lane & 15, quad = lane >> 4;
    int bt = m0 >> 10;                    // batch (128 | 1024, uniform per block)

    int srow = wave * 32 + (lane >> 2);
    int scol = (lane & 3) * 8;
    const u16* Bg = Btq + (long)(n0 + srow) * DIMD + scol;
    u16* Bsl = Bs + wave * 1024 + lane * 8;

    f32x4 acc[4][4];
    #pragma unroll
    for (int i = 0; i < 4; i++)
        #pragma unroll
        for (int j = 0; j < 4; j++)
            acc[i][j] = (f32x4){0.f, 0.f, 0.f, 0.f};

    for (int k0 = 0; k0 < DIMD; k0 += 32) {
        __syncthreads();
        gload16(Bg + k0, Bsl);
        gload16(Bg + 16 * DIMD + k0, Bsl + 512);
        // A staging: LN+FiLM inline, 2 chunks of 8 elements per thread
        #pragma unroll
        for (int u = 0; u < 2; u++) {
            int idx = t + u * 256;            // 0..511
            int r = idx >> 2;                 // row 0..127
            int c8 = (idx & 3) * 8;           // col 0,8,16,24
            long grow = m0 + r;
            int col = k0 + c8;
            const float* xp = &query[grow * DIMD + col];
            float4 x0 = *(const float4*)xp, x1 = *(const float4*)(xp + 4);
            float mu = mu_q[grow], rs = rs_q[grow];
            float4 g0 = *(const float4*)&qn_g[col], g1 = *(const float4*)&qn_g[col + 4];
            float4 b0 = *(const float4*)&qn_b[col], b1 = *(const float4*)&qn_b[col + 4];
            const float* gp = gamma + bt * DIMD + col;
            const float* bp = beta + bt * DIMD + col;
            float4 gm0 = *(const float4*)gp, gm1 = *(const float4*)(gp + 4);
            float4 be0 = *(const float4*)bp, be1 = *(const float4*)(bp + 4);
            u16 o8[8];
            o8[0] = f2bf(((x0.x - mu) * rs * g0.x + b0.x) * (1.f + gm0.x) + be0.x);
            o8[1] = f2bf(((x0.y - mu) * rs * g0.y + b0.y) * (1.f + gm0.y) + be0.y);
            o8[2] = f2bf(((x0.z - mu) * rs * g0.z + b0.z) * (1.f + gm0.z) + be0.z);
            o8[3] = f2bf(((x0.w - mu) * rs * g0.w + b0.w) * (1.f + gm0.w) + be0.w);
            o8[4] = f2bf(((x1.x - mu) * rs * g1.x + b1.x) * (1.f + gm1.x) + be1.x);
            o8[5] = f2bf(((x1.y - mu) * rs * g1.y + b1.y) * (1.f + gm1.y) + be1.y);
            o8[6] = f2bf(((x1.z - mu) * rs * g1.z + b1.z) * (1.f + gm1.z) + be1.z);
            o8[7] = f2bf(((x1.w - mu) * rs * g1.w + b1.w) * (1.f + gm1.w) + be1.w);
            *(int4*)&As[r * 32 + c8] = *(const int4*)o8;
        }
        __syncthreads();
        bf16x8 af[4], bfr[4];
        #pragma unroll
        for (int i = 0; i < 4; i++) {
            af[i]  = *(const bf16x8*)&As[(mhalf + i * 16 + lm) * 32 + quad * 8];
            bfr[i] = *(const bf16x8*)&Bs[(nhalf + i * 16 + lm) * 32 + quad * 8];
        }
        #pragma unroll
        for (int i = 0; i < 4; i++)
            #pragma unroll
            for (int j = 0; j < 4; j++)
                acc[i][j] = __builtin_amdgcn_mfma_f32_16x16x32_bf16(af[i], bfr[j], acc[i][j], 0, 0, 0);
    }

    float biasj[4];
    #pragma unroll
    for (int j = 0; j < 4; j++) biasj[j] = biasq[n0 + nhalf + j * 16 + lm];

    for (int i = 0; i < 4; i++) {
        __syncthreads();
        #pragma unroll
        for (int j = 0; j < 4; j++)
            #pragma unroll
            for (int r = 0; r < 4; r++)
                smem[((wave >> 1) * 16 + quad * 4 + r) * 128 + nhalf + j * 16 + lm] =
                    f2bf(acc[i][j][r] + biasj[j]);
        __syncthreads();
        #pragma unroll
        for (int u = 0; u < 2; u++) {
            int cch = t + u * 256;
            int R = cch >> 4, ci = cch & 15;
            long grow = m0 + (R >> 4) * 64 + i * 16 + (R & 15);
            int gcol = n0 + ci * 8;
            int4 val = *(const int4*)&smem[R * 128 + ci * 8];
            if (gcol < 512)       *(int4*)(qp + grow * 512 + gcol) = val;
            else if (gcol < 544)  *(int4*)(gq + grow * 32 + (gcol - 512)) = val;
        }
    }
}

// ===========================================================================
// K5: output projection (fp32 out), counted dbuf GEMM
// ===========================================================================
__global__ __launch_bounds__(256) void ogemm_kernel(
    const u16* __restrict__ ctxb, const u16* __restrict__ Bto,
    const float* __restrict__ bo, float* __restrict__ out)
{
    __shared__ u16 smem[32768];
    gemm_body<1, false>(blockIdx.x, ctxb, Bto, bo, out, nullptr, nullptr, 512, 4, 8, smem);
}

// ===========================================================================
// K4: Flash-style local attention, 2-step-deep register K/V prefetch.
// ===========================================================================
__global__ __launch_bounds__(256, 2) void attn_kernel(
    const u16* __restrict__ q_bf, const u16* __restrict__ k_bf,
    const u16* __restrict__ v_bf, const u16* __restrict__ gq_bf,
    const u16* __restrict__ gk_bf, u16* __restrict__ ctx)
{
    __shared__ u16 Ks[16 * 512];
    __shared__ u16 Vt[512 * 32];
    __shared__ u16 Pb[16 * 40];
    __shared__ float part[4][16][16];
    __shared__ float Gb[16][16];
    __shared__ float alphap[16];
    __shared__ float linv[16];

    int blk = blockIdx.x;
    int b = blk >> 6, qs = blk & 63;
    int center = (int)(qs * (255.0f / 63.0f) + 0.5f);
    int lo = center - WIN; if (lo < 0) lo = 0;
    int hi = center + WIN; if (hi > KS - 1) hi = KS - 1;
    int nst = hi - lo + 1;
    long rowq0 = (long)b * NQ + qs * 16;
    long rowk0 = (long)b * NK + lo * 16;

    int t = threadIdx.x;
    int wave = t >> 6, lane = t & 63;
    int lm = lane & 15, quad = lane >> 4;
    int qi = t >> 4, ki = t & 15;

    bf16x8 qf[4];
    #pragma unroll
    for (int f = 0; f < 4; f++)
        qf[f] = *(const bf16x8*)&q_bf[(rowq0 + lm) * DIMD + wave * 128 + f * 32 + quad * 8];
    bf16x8 gqf;
    if (wave == 3) gqf = *(const bf16x8*)&gq_bf[(rowq0 + lm) * RANK + quad * 8];

    // 2-deep prefetch register sets
    int4 kA[4], vA[4], kB[4], vB[4];

    auto loadset = [&](int s, int4 (&kp_)[4], int4 (&vp_)[4]) {
        long rk = rowk0 + (long)s * 16;
        #pragma unroll
        for (int u = 0; u < 4; u++) {
            int idx = u * 256 + t;
            kp_[u] = *(const int4*)&k_bf[(rk + (idx >> 6)) * DIMD + (idx & 63) * 8];
            int vkv = (idx >> 2) & 15, vdc = (idx & 3) | ((idx >> 6) << 2);
            vp_[u] = *(const int4*)&v_bf[(rk + vkv) * DIMD + vdc * 8];
        }
    };

    loadset(0, kA, vA);
    if (nst > 1) loadset(1, kB, vB);

    float m_run = -1e30f, l_run = 0.f;
    f32x4 acc[8];
    #pragma unroll
    for (int j = 0; j < 8; j++) acc[j] = (f32x4){0.f, 0.f, 0.f, 0.f};

    const float scale = 0.044194173824159216f;   // 512^-0.5
    const float grs = 0.17677669529663687f;      // 32^-0.5

    auto step_body = [&](int s, int4 (&kcur)[4], int4 (&vcur)[4]) {
        int half = s & 1;
        #pragma unroll
        for (int u = 0; u < 4; u++) {
            int idx = u * 256 + t;
            int row = idx >> 6, c = idx & 63;
            *(int4*)&Ks[row * 512 + (c ^ (row & 7)) * 8] = kcur[u];
            int vkv = (idx >> 2) & 15, vdc = (idx & 3) | ((idx >> 6) << 2);
            int kvp = half * 16 + vkv;
            u16 vv[8];
            *(int4*)vv = vcur[u];
            #pragma unroll
            for (int i = 0; i < 8; i++) {
                int d = vdc * 8 + i;
                Vt[d * 32 + (((kvp >> 3) ^ (d & 3)) << 3) + (kvp & 7)] = vv[i];
            }
        }
        __syncthreads();
        if (s + 2 < nst) loadset(s + 2, kcur, vcur);

        f32x4 sacc = (f32x4){0.f, 0.f, 0.f, 0.f};
        #pragma unroll
        for (int f = 0; f < 4; f++) {
            int cidx = wave * 16 + f * 4 + quad;
            bf16x8 kf = *(const bf16x8*)&Ks[lm * 512 + (cidx ^ (lm & 7)) * 8];
            sacc = __builtin_amdgcn_mfma_f32_16x16x32_bf16(qf[f], kf, sacc, 0, 0, 0);
        }
        #pragma unroll
        for (int r = 0; r < 4; r++) part[wave][quad * 4 + r][lm] = sacc[r];
        if (wave == 3) {
            bf16x8 gkf = *(const bf16x8*)&gk_bf[(rowk0 + (long)s * 16 + lm) * RANK + quad * 8];
            f32x4 gacc = (f32x4){0.f, 0.f, 0.f, 0.f};
            gacc = __builtin_amdgcn_mfma_f32_16x16x32_bf16(gqf, gkf, gacc, 0, 0, 0);
            #pragma unroll
            for (int r = 0; r < 4; r++) Gb[quad * 4 + r][lm] = gacc[r];
        }
        __syncthreads();
        float sv = (part[0][qi][ki] + part[1][qi][ki] + part[2][qi][ki] + part[3][qi][ki]) * scale;
        float gl = Gb[qi][ki] * grs;
        float sig = 1.f / (1.f + expf(-gl));
        sv += logf(sig + 1e-6f);
        float mx = sv;
        mx = fmaxf(mx, __shfl_xor(mx, 1));
        mx = fmaxf(mx, __shfl_xor(mx, 2));
        mx = fmaxf(mx, __shfl_xor(mx, 4));
        mx = fmaxf(mx, __shfl_xor(mx, 8));
        float m_new = fmaxf(m_run, mx);
        float p = expf(sv - m_new);
        float ps = p;
        ps += __shfl_xor(ps, 1);
        ps += __shfl_xor(ps, 2);
        ps += __shfl_xor(ps, 4);
        ps += __shfl_xor(ps, 8);
        float alpha = expf(m_run - m_new);
        l_run = l_run * alpha + ps;
        m_run = m_new;
        Pb[qi * 40 + half * 16 + ki] = f2bf(p);
        if (half == 1) {
            Pb[qi * 40 + ki] = f2bf(bf2f(Pb[qi * 40 + ki]) * alpha);
        }
        bool dopv = (half == 1) || (s == nst - 1);
        if (dopv && half == 0) Pb[qi * 40 + 16 + ki] = 0;
        if (ki == 0) {
            if (half == 0) alphap[qi] = alpha;
            else           alphap[qi] *= alpha;
            if (s == nst - 1) linv[qi] = 1.f / l_run;
        }
        __syncthreads();
        if (dopv) {
            float ar[4];
            #pragma unroll
            for (int r = 0; r < 4; r++) ar[r] = alphap[quad * 4 + r];
            #pragma unroll
            for (int j = 0; j < 8; j++)
                #pragma unroll
                for (int r = 0; r < 4; r++) acc[j][r] *= ar[r];
            bf16x8 pf = *(const bf16x8*)&Pb[lm * 40 + quad * 8];
            #pragma unroll
            for (int j = 0; j < 8; j++) {
                int d = wave * 128 + j * 16 + lm;
                bf16x8 vf = *(const bf16x8*)&Vt[d * 32 + ((quad ^ (d & 3)) << 3)];
                acc[j] = __builtin_amdgcn_mfma_f32_16x16x32_bf16(pf, vf, acc[j], 0, 0, 0);
            }
            __syncthreads();
        }
    };

    for (int s = 0; s < nst; s++) {
        if ((s & 1) == 0) step_body(s, kA, vA);
        else              step_body(s, kB, vB);
    }

    float li[4];
    #pragma unroll
    for (int r = 0; r < 4; r++) li[r] = linv[quad * 4 + r];
    #pragma unroll
    for (int j = 0; j < 8; j++) {
        int d = wave * 128 + j * 16 + lm;
        #pragma unroll
        for (int r = 0; r < 4; r++)
            ctx[(rowq0 + quad * 4 + r) * DIMD + d] = f2bf(acc[j][r] * li[r]);
    }
}

// ---------------------------------------------------------------------------
extern "C" void kernel_launch(void* const* d_in, const int* in_sizes, int n_in,
                              void* d_out, int out_size, void* d_ws, size_t ws_size,
                              hipStream_t stream) {
    const float* query  = (const float*)d_in[0];
    const float* source = (const float*)d_in[1];
    const float* ctx0   = (const float*)d_in[2];
    const float* ctx1   = (const float*)d_in[3];
    // d_in[4] = mask: structurally known local window, unused
    const float* qn_g  = (const float*)d_in[5];
    const float* qn_b  = (const float*)d_in[6];
    const float* kvn_g = (const float*)d_in[7];
    const float* kvn_b = (const float*)d_in[8];
    const float* Wq = (const float*)d_in[9];   const float* bq = (const float*)d_in[10];
    const float* Wk = (const float*)d_in[11];  const float* bk = (const float*)d_in[12];
    const float* Wv = (const float*)d_in[13];  const float* bv = (const float*)d_in[14];
    const float* Wo = (const float*)d_in[15];  const float* bo = (const float*)d_in[16];
    const float* Wgq = (const float*)d_in[17];
    const float* Wgk = (const float*)d_in[18];
    const float* Wc0 = (const float*)d_in[19]; const float* bc0 = (const float*)d_in[20];
    const float* Wc1 = (const float*)d_in[21]; const float* bc1 = (const float*)d_in[22];
    const float* Wf  = (const float*)d_in[23]; const float* bfv = (const float*)d_in[24];

    // ---- workspace layout ----
    float* ws = (float*)d_ws;
    float* h      = ws;                         // 4096
    float* gamma  = h + 4096;                   // 4096
    float* beta   = gamma + 4096;               // 4096
    float* biaskv = beta + 4096;                // 1152
    float* biasq  = biaskv + 1152;              // 640
    float* mu_q   = biasq + 640;                // 8192
    float* rs_q   = mu_q + 8192;                // 8192
    u16* u = (u16*)(rs_q + 8192);
    u16* sln  = u;                 u += (long)MK * DIMD;   // LN(source) bf16
    u16* kp   = u;                 u += (long)MK * DIMD;   // k proj bf16
    u16* vp   = u;                 u += (long)MK * DIMD;   // v proj bf16
    u16* gk   = u;                 u += (long)MK * RANK;   // gate_k bf16
    u16* gq   = u;                 u += (long)MQ * RANK;   // gate_q bf16
    u16* qp   = u;                 u += (long)MQ * DIMD;   // q proj bf16
    u16* ctxb = u;                 u += (long)MQ * DIMD;   // attention output bf16
    u16* Btkv = u;                 u += 1152L * DIMD;      // [Wk^T | Wv^T | (Wk·Wgk)^T]
    u16* Btq  = u;                 u += 640L * DIMD;       // [Wq^T | (Wq·Wgq)^T]
    u16* Bto  = u;                 u += 512L * DIMD;       // Wo^T
    float* out = (float*)d_out;

    // K1a: weight-space prep (small LDS, chain-split bodies)
    prep_w_kernel<<<PW_TOTAL, 256, 0, stream>>>(
        ctx0, ctx1, Wc0, bc0, Wc1, bc1, h,
        Wk, Wv, Wq, Wo, Btkv, Btq, Bto,
        Wgk, Wgq, bk, bv, bq, biaskv, biasq);

    // K1b: max-TLP streaming (stats + norm0), zero LDS, 32 waves/CU
    prep_s_kernel<<<PS_BLOCKS, 256, 0, stream>>>(
        query, mu_q, rs_q, source, kvn_g, kvn_b, sln);

    // K2: film_gb + kv projection GEMM (counted-vmcnt dbuf)
    kv_kernel<<<256 + 2304, 256, 0, stream>>>(
        h, Wf, bfv, gamma, beta, sln, Btkv, biaskv, kp, vp, gk);

    // K3: q projection GEMM (LN+FiLM inline)
    qproj_kernel<<<320, 256, 0, stream>>>(
        query, mu_q, rs_q, qn_g, qn_b, gamma, beta, Btq, biasq, qp, gq);

    // K4: flash local attention (2-deep K/V prefetch)
    attn_kernel<<<BATCH * QS, 256, 0, stream>>>(qp, kp, vp, gq, gk, ctxb);

    // K5: output projection (fp32 out)
    ogemm_kernel<<<256, 256, 0, stream>>>(ctxb, Bto, bo, out);
}